// Round 1
// baseline (126.332 us; speedup 1.0000x reference)
//
#include <hip/hip_runtime.h>
#include <hip/hip_bf16.h>
#include <stdint.h>

#define BATCH 4
#define CCH   64
#define NPIX  4096
#define DQK   8

typedef __attribute__((ext_vector_type(8)))  short bf16x8;
typedef __attribute__((ext_vector_type(16))) float f32x16;

static __device__ __forceinline__ short f2bf(float f) {
    union { __hip_bfloat16 h; short s; } u;
    u.h = __float2bfloat16(f);
    return u.s;
}

// ---------------------------------------------------------------------------
// Projection kernel: q = (Wq x + bq)*scale, k = Wk x + bk, v = Wv x + bv
// q,k stored [B][N][8] bf16 (16B per pixel row = one MFMA fragment)
// v stored   [B][C][N] bf16
// ---------------------------------------------------------------------------
__global__ __launch_bounds__(256) void proj_kernel(
    const float* __restrict__ x,
    const float* __restrict__ Wq, const float* __restrict__ bq,
    const float* __restrict__ Wk, const float* __restrict__ bk,
    const float* __restrict__ Wv, const float* __restrict__ bv,
    short* __restrict__ qo, short* __restrict__ ko, short* __restrict__ vo)
{
    __shared__ float xs[CCH][64];      // x tile [c][pixel]
    __shared__ float wv_s[CCH][CCH];   // Wv transposed: [c][e]
    __shared__ float wq_s[CCH][DQK];   // [c][d]
    __shared__ float wk_s[CCH][DQK];

    const int b  = blockIdx.x >> 6;
    const int n0 = (blockIdx.x & 63) << 6;
    const int tid = threadIdx.x;

    for (int i = tid; i < CCH*CCH; i += 256) wv_s[i & 63][i >> 6] = Wv[i];
    for (int i = tid; i < CCH*DQK; i += 256) { wq_s[i & 63][i >> 6] = Wq[i]; wk_s[i & 63][i >> 6] = Wk[i]; }
    for (int i = tid; i < CCH*64; i += 256) {
        int c = i >> 6, p = i & 63;
        xs[c][p] = x[((size_t)b*CCH + c)*NPIX + n0 + p];
    }
    __syncthreads();

    const int p = tid & 63;
    const int g = tid >> 6;       // 0..3: 16 v-channels + 2 q/k dims each
    const int e0 = g * 16, d0 = g * 2;

    float av[16];
    #pragma unroll
    for (int i = 0; i < 16; ++i) av[i] = bv[e0 + i];
    float aq0 = bq[d0], aq1 = bq[d0+1];
    float ak0 = bk[d0], ak1 = bk[d0+1];

    for (int c = 0; c < CCH; ++c) {
        float xv = xs[c][p];
        const float4* wrow = (const float4*)&wv_s[c][e0];
        #pragma unroll
        for (int q4 = 0; q4 < 4; ++q4) {
            float4 w = wrow[q4];
            av[q4*4+0] += w.x * xv;
            av[q4*4+1] += w.y * xv;
            av[q4*4+2] += w.z * xv;
            av[q4*4+3] += w.w * xv;
        }
        float2 q2 = *(const float2*)&wq_s[c][d0];
        float2 k2 = *(const float2*)&wk_s[c][d0];
        aq0 += q2.x * xv; aq1 += q2.y * xv;
        ak0 += k2.x * xv; ak1 += k2.y * xv;
    }

    const float scale = 0.35355339059327373f;  // 1/sqrt(8), folded into q
    const size_t vb = (size_t)b * CCH * NPIX;
    #pragma unroll
    for (int i = 0; i < 16; ++i)
        vo[vb + (size_t)(e0 + i)*NPIX + n0 + p] = f2bf(av[i]);
    const size_t qb = ((size_t)b*NPIX + n0 + p)*DQK + d0;
    qo[qb]   = f2bf(aq0 * scale);
    qo[qb+1] = f2bf(aq1 * scale);
    ko[qb]   = f2bf(ak0);
    ko[qb+1] = f2bf(ak1);
}

// ---------------------------------------------------------------------------
// Flash attention: block = 32 queries, 4 waves = 4 j-splits of 1024, merged
// in LDS. Swapped QK^T (mfma(K,Q)) so softmax is lane-local + one shfl_xor.
// ---------------------------------------------------------------------------
__global__ __launch_bounds__(256) void attn_kernel(
    const short* __restrict__ qg, const short* __restrict__ kg,
    const short* __restrict__ vg,
    const float* __restrict__ x, const float* __restrict__ gamma,
    float* __restrict__ outp)
{
    __shared__ float m_s[4][32];
    __shared__ float l_s[4][32];
    __shared__ float acc_s[64][32];                 // merged output tile
    __shared__ __align__(16) short ps_s[4][32*40];  // per-wave P buffer, 80B rows

    const int b  = blockIdx.x >> 7;        // 128 query tiles per batch
    const int i0 = (blockIdx.x & 127) << 5;
    const int tid  = threadIdx.x;
    const int wave = tid >> 6, lane = tid & 63;
    const int hi = lane >> 5, li = lane & 31;

    for (int i = tid; i < 64*32; i += 256) acc_s[i >> 5][i & 31] = 0.f;
    __syncthreads();

    bf16x8 zf;
    #pragma unroll
    for (int i = 0; i < 8; ++i) zf[i] = 0;
    f32x16 z16;
    #pragma unroll
    for (int r = 0; r < 16; ++r) z16[r] = 0.f;

    // Q fragment: B-operand [16 d][32 i]; lane holds col i=li, d = hi*8..hi*8+7
    bf16x8 qf = zf;
    if (hi == 0) qf = *(const bf16x8*)&qg[((size_t)b*NPIX + i0 + li)*DQK];

    f32x16 acc0 = z16, acc1 = z16;
    float m_run = -1e30f, l_run = 0.f;
    short* psb = &ps_s[wave][0];
    const size_t kbase = (size_t)b * NPIX * DQK;
    const size_t vbase = (size_t)b * CCH * NPIX;

    const int jbeg = wave << 10, jend = jbeg + 1024;
    for (int j0 = jbeg; j0 < jend; j0 += 32) {
        // S-tile: A = K rows [32 j][16 d(pad)], lane row j=li, d=hi*8..+7
        bf16x8 ak = zf;
        if (hi == 0) ak = *(const bf16x8*)&kg[kbase + (size_t)(j0 + li)*DQK];
        f32x16 S = __builtin_amdgcn_mfma_f32_32x32x16_bf16(ak, qf, z16, 0, 0, 0);
        // lane holds S[j][i]: col i = li (query), rows j = (r&3)+8*(r>>2)+4*hi

        // online softmax over this lane's 16 j + partner half
        float mx = S[0];
        #pragma unroll
        for (int r = 1; r < 16; ++r) mx = fmaxf(mx, S[r]);
        mx = fmaxf(mx, __shfl_xor(mx, 32));
        float m_new = fmaxf(m_run, mx);
        float fr = __expf(m_run - m_new);
        float p[16], ts = 0.f;
        #pragma unroll
        for (int r = 0; r < 16; ++r) { p[r] = __expf(S[r] - m_new); ts += p[r]; }
        ts += __shfl_xor(ts, 32);
        l_run = l_run * fr + ts;
        m_run = m_new;
        #pragma unroll
        for (int r = 0; r < 16; ++r) { acc0[r] *= fr; acc1[r] *= fr; }

        // write P (bf16 pairs along j) into wave-private LDS: ps[i=li][j]
        #pragma unroll
        for (int rp = 0; rp < 8; ++rp) {
            int r = rp * 2;
            int j = (r & 3) + ((r >> 2) << 3) + (hi << 2);
            uint32_t pk = (uint32_t)(uint16_t)f2bf(p[r]) |
                          ((uint32_t)(uint16_t)f2bf(p[r+1]) << 16);
            *(uint32_t*)((char*)psb + li*80 + j*2) = pk;
        }

        // PV: out[c][i] += V[32c][16j] · P[16j][32i], 2 c-tiles × 2 j-subtiles
        #pragma unroll
        for (int sub = 0; sub < 2; ++sub) {
            bf16x8 bp = *(const bf16x8*)((char*)psb + li*80 + (sub*16 + hi*8)*2);
            const short* vrow = &vg[vbase + (size_t)li*NPIX + j0 + sub*16 + hi*8];
            bf16x8 av0 = *(const bf16x8*)vrow;
            bf16x8 av1 = *(const bf16x8*)(vrow + (size_t)32*NPIX);
            acc0 = __builtin_amdgcn_mfma_f32_32x32x16_bf16(av0, bp, acc0, 0, 0, 0);
            acc1 = __builtin_amdgcn_mfma_f32_32x32x16_bf16(av1, bp, acc1, 0, 0, 0);
        }
    }

    // merge the 4 j-splits
    if (hi == 0) { m_s[wave][li] = m_run; l_s[wave][li] = l_run; }
    __syncthreads();
    float M = fmaxf(fmaxf(m_s[0][li], m_s[1][li]), fmaxf(m_s[2][li], m_s[3][li]));
    float F = __expf(m_run - M);
    for (int w = 0; w < 4; ++w) {
        if (wave == w) {
            #pragma unroll
            for (int r = 0; r < 16; ++r) {
                int crow = (r & 3) + ((r >> 2) << 3) + (hi << 2);
                acc_s[crow][li]      += acc0[r] * F;
                acc_s[crow + 32][li] += acc1[r] * F;
            }
        }
        __syncthreads();
    }

    const float g0 = gamma[0];
    for (int idx = tid; idx < 64*32; idx += 256) {
        int c = idx >> 5, i = idx & 31;
        float Mq = fmaxf(fmaxf(m_s[0][i], m_s[1][i]), fmaxf(m_s[2][i], m_s[3][i]));
        float L = l_s[0][i]*__expf(m_s[0][i]-Mq) + l_s[1][i]*__expf(m_s[1][i]-Mq)
                + l_s[2][i]*__expf(m_s[2][i]-Mq) + l_s[3][i]*__expf(m_s[3][i]-Mq);
        size_t gidx = vbase + (size_t)c*NPIX + i0 + i;
        outp[gidx] = g0 * (acc_s[c][i] / L) + x[gidx];
    }
}

extern "C" void kernel_launch(void* const* d_in, const int* in_sizes, int n_in,
                              void* d_out, int out_size, void* d_ws, size_t ws_size,
                              hipStream_t stream) {
    const float* x     = (const float*)d_in[0];
    const float* Wq    = (const float*)d_in[1];
    const float* bq    = (const float*)d_in[2];
    const float* Wk    = (const float*)d_in[3];
    const float* bk    = (const float*)d_in[4];
    const float* Wv    = (const float*)d_in[5];
    const float* bv    = (const float*)d_in[6];
    const float* gamma = (const float*)d_in[7];

    short* qo = (short*)d_ws;                        // [B][N][8] bf16
    short* ko = qo + (size_t)BATCH*NPIX*DQK;         // [B][N][8] bf16
    short* vo = ko + (size_t)BATCH*NPIX*DQK;         // [B][C][N] bf16

    proj_kernel<<<BATCH*(NPIX/64), 256, 0, stream>>>(x, Wq, bq, Wk, bk, Wv, bv, qo, ko, vo);
    attn_kernel<<<BATCH*(NPIX/32), 256, 0, stream>>>(qo, ko, vo, x, gamma, (float*)d_out);
}